// Round 1
// baseline (1023.091 us; speedup 1.0000x reference)
//
#include <hip/hip_runtime.h>
#include <stdint.h>

// ---------------------------------------------------------------------------
// VQVAE-with-attention forward, MI355X (gfx950).
// All GEMMs: bf16 MFMA 16x16x32, 128x128 tile, BK=64, 4 waves (2x2), m97-style
// global_load_lds staging. Inputs f32 -> converted to bf16 in ws; output f32.
// WS budget ~192 MB (assumed available).
// ---------------------------------------------------------------------------

typedef unsigned short u16;
typedef __attribute__((ext_vector_type(8))) short short8;
typedef __attribute__((ext_vector_type(4))) float f32x4;

#define B_SZ 16384
#define DIN 1280
#define DH 1024
#define DE 512
#define KCB 8192

#define BM 128
#define BN 128
#define BK 64

__device__ __forceinline__ float bf2f(u16 u) {
  union { unsigned int u; float f; } v; v.u = ((unsigned int)u) << 16; return v.f;
}
__device__ __forceinline__ u16 f2bf(float f) {
  union { float f; unsigned int u; } v; v.f = f;
  unsigned int r = v.u + 0x7FFFu + ((v.u >> 16) & 1u);  // RNE
  return (u16)(r >> 16);
}
__device__ __forceinline__ void async16(const u16* g, u16* l) {
  __builtin_amdgcn_global_load_lds((__attribute__((address_space(1))) void*)(g),
                                   (__attribute__((address_space(3))) void*)(l),
                                   16, 0, 0);
}
__device__ __forceinline__ float wave_sum(float s) {
  #pragma unroll
  for (int m = 1; m < 64; m <<= 1) s += __shfl_xor(s, m, 64);
  return s;
}

// f32 -> bf16 conversion, 4 elems/thread
__global__ __launch_bounds__(256) void k_f2bf(const float* __restrict__ in,
                                              u16* __restrict__ out, int n) {
  int i = (blockIdx.x * 256 + threadIdx.x) * 4;
  if (i < n) {
    float4 v = *(const float4*)(in + i);
    ushort4 o;
    o.x = f2bf(v.x); o.y = f2bf(v.y); o.z = f2bf(v.z); o.w = f2bf(v.w);
    *(ushort4*)(out + i) = o;
  }
}

// per-codebook-row squared norms; wave per row
__global__ __launch_bounds__(256) void k_cnorm(const float* __restrict__ cb,
                                               float* __restrict__ cnorm) {
  int row = blockIdx.x * 4 + (threadIdx.x >> 6);
  int lane = threadIdx.x & 63;
  const float* r = cb + (size_t)row * DE;
  float s = 0.f;
  #pragma unroll
  for (int i = 0; i < DE / 64; ++i) { float v = r[lane + i * 64]; s += v * v; }
  s = wave_sum(s);
  if (lane == 0) cnorm[row] = s;
}

// MODE: 0 bias->bf16, 1 bias+res->bf16, 2 bias+relu->bf16,
//       3 bias+relu+res->bf16, 4 bias+relu->f32, 5 argmin partials
template <int MODE>
__global__ __launch_bounds__(256)
void k_gemm(const u16* __restrict__ A, const u16* __restrict__ W,
            const float* __restrict__ bias, const u16* __restrict__ Res,
            u16* __restrict__ O, float* __restrict__ Of,
            const float* __restrict__ cnorm,
            float* __restrict__ partv, int* __restrict__ parti,
            int M, int N, int K) {
  __shared__ u16 lA[BM * BK];  // 16 KB, linear [row][k]
  __shared__ u16 lB[BN * BK];  // 16 KB
  const int tid = threadIdx.x;
  const int m0 = blockIdx.x * BM;
  const int n0 = blockIdx.y * BN;
  const int w = tid >> 6, lane = tid & 63;
  const int wm = w >> 1, wn = w & 1;       // 2x2 waves, each 64x64
  const int lr = lane & 15, lk = lane >> 4;

  f32x4 acc[4][4];
  #pragma unroll
  for (int m = 0; m < 4; ++m)
    #pragma unroll
    for (int n = 0; n < 4; ++n) acc[m][n] = (f32x4){0.f, 0.f, 0.f, 0.f};

  const int rA = tid >> 3;          // staging row within 32-row chunk
  const int cA = (tid & 7) * 8;     // staging col (elems)
  const u16* pA = A + (size_t)(m0 + rA) * K + cA;
  const u16* pB = W + (size_t)(n0 + rA) * K + cA;

  for (int k0 = 0; k0 < K; k0 += BK) {
    #pragma unroll
    for (int c = 0; c < 4; ++c) {
      async16(pA + (size_t)(c * 32) * K + k0, &lA[c * 2048 + tid * 8]);
      async16(pB + (size_t)(c * 32) * K + k0, &lB[c * 2048 + tid * 8]);
    }
    __syncthreads();
    #pragma unroll
    for (int ks = 0; ks < 2; ++ks) {
      short8 af[4], bfr[4];
      #pragma unroll
      for (int m = 0; m < 4; ++m)
        af[m] = *(const short8*)&lA[(wm * 64 + m * 16 + lr) * BK + ks * 32 + lk * 8];
      #pragma unroll
      for (int n = 0; n < 4; ++n)
        bfr[n] = *(const short8*)&lB[(wn * 64 + n * 16 + lr) * BK + ks * 32 + lk * 8];
      #pragma unroll
      for (int m = 0; m < 4; ++m)
        #pragma unroll
        for (int n = 0; n < 4; ++n)
          acc[m][n] = __builtin_amdgcn_mfma_f32_16x16x32_bf16(af[m], bfr[n], acc[m][n], 0, 0, 0);
    }
    __syncthreads();
  }

  if constexpr (MODE == 5) {
    // distance argmin within this 128-col block: d2 = cnorm[c] - 2*(z.c)
    __shared__ float sv[2][BM];
    __shared__ int si[2][BM];
    #pragma unroll
    for (int m = 0; m < 4; ++m) {
      #pragma unroll
      for (int j = 0; j < 4; ++j) {
        float bv = 3.0e38f; int bc = 0;
        #pragma unroll
        for (int n = 0; n < 4; ++n) {
          int gc = n0 + wn * 64 + n * 16 + lr;
          float v = cnorm[gc] - 2.0f * acc[m][n][j];
          if (v < bv) { bv = v; bc = gc; }
        }
        #pragma unroll
        for (int mask = 1; mask < 16; mask <<= 1) {
          float ov = __shfl_xor(bv, mask, 64);
          int oc = __shfl_xor(bc, mask, 64);
          if (ov < bv || (ov == bv && oc < bc)) { bv = ov; bc = oc; }
        }
        if (lr == 0) {
          int rl = wm * 64 + m * 16 + lk * 4 + j;
          sv[wn][rl] = bv; si[wn][rl] = bc;
        }
      }
    }
    __syncthreads();
    if (tid < BM) {
      float v0 = sv[0][tid], v1 = sv[1][tid];
      int i0 = si[0][tid], i1 = si[1][tid];
      float v = v0; int ii = i0;
      if (v1 < v0 || (v1 == v0 && i1 < i0)) { v = v1; ii = i1; }
      int nkb = gridDim.y;
      partv[(size_t)(m0 + tid) * nkb + blockIdx.y] = v;
      parti[(size_t)(m0 + tid) * nkb + blockIdx.y] = ii;
    }
  } else {
    #pragma unroll
    for (int m = 0; m < 4; ++m) {
      int gr = m0 + wm * 64 + m * 16 + lk * 4;
      #pragma unroll
      for (int n = 0; n < 4; ++n) {
        int gc = n0 + wn * 64 + n * 16 + lr;
        float bb = bias[gc];
        #pragma unroll
        for (int j = 0; j < 4; ++j) {
          float v = acc[m][n][j] + bb;
          if constexpr (MODE == 2 || MODE == 3 || MODE == 4) v = fmaxf(v, 0.f);
          if constexpr (MODE == 1 || MODE == 3) v += bf2f(Res[(size_t)(gr + j) * N + gc]);
          if constexpr (MODE == 4) Of[(size_t)(gr + j) * N + gc] = v;
          else O[(size_t)(gr + j) * N + gc] = f2bf(v);
        }
      }
    }
  }
}

// LayerNorm over DH=1024, wave per row, 16 elems/lane
__global__ __launch_bounds__(256)
void k_ln(const u16* __restrict__ X, const float* __restrict__ g,
          const float* __restrict__ b, u16* __restrict__ O) {
  int row = blockIdx.x * 4 + (threadIdx.x >> 6);
  int lane = threadIdx.x & 63;
  const u16* xr = X + (size_t)row * DH + lane * 16;
  uint4 d0 = *(const uint4*)(xr);
  uint4 d1 = *(const uint4*)(xr + 8);
  unsigned int ww[8] = {d0.x, d0.y, d0.z, d0.w, d1.x, d1.y, d1.z, d1.w};
  float v[16];
  #pragma unroll
  for (int i = 0; i < 8; ++i) {
    v[2 * i] = bf2f((u16)(ww[i] & 0xffff));
    v[2 * i + 1] = bf2f((u16)(ww[i] >> 16));
  }
  float s = 0.f;
  #pragma unroll
  for (int i = 0; i < 16; ++i) s += v[i];
  s = wave_sum(s);
  float mean = s * (1.0f / DH);
  float q = 0.f;
  #pragma unroll
  for (int i = 0; i < 16; ++i) { float d = v[i] - mean; q += d * d; }
  q = wave_sum(q);
  float rstd = rsqrtf(q * (1.0f / DH) + 1e-5f);
  int base = lane * 16;
  unsigned int ow[8];
  #pragma unroll
  for (int i = 0; i < 8; ++i) {
    float a0 = (v[2 * i] - mean) * rstd * g[base + 2 * i] + b[base + 2 * i];
    float a1 = (v[2 * i + 1] - mean) * rstd * g[base + 2 * i + 1] + b[base + 2 * i + 1];
    ow[i] = (unsigned int)f2bf(a0) | ((unsigned int)f2bf(a1) << 16);
  }
  uint4 o0 = {ow[0], ow[1], ow[2], ow[3]};
  uint4 o1 = {ow[4], ow[5], ow[6], ow[7]};
  *(uint4*)(O + (size_t)row * DH + lane * 16) = o0;
  *(uint4*)(O + (size_t)row * DH + lane * 16 + 8) = o1;
}

// final argmin over 64 partials/row, gather codebook row (overwrite z with
// quant in-place), accumulate sum((quant-z)^2)
__global__ __launch_bounds__(256)
void k_argmin_fin(const float* __restrict__ partv, const int* __restrict__ parti,
                  const float* __restrict__ cb, u16* __restrict__ zq,
                  float* __restrict__ loss) {
  int row = blockIdx.x * 4 + (threadIdx.x >> 6);
  int lane = threadIdx.x & 63;
  float v = partv[(size_t)row * 64 + lane];
  int idx = parti[(size_t)row * 64 + lane];
  #pragma unroll
  for (int m = 1; m < 64; m <<= 1) {
    float ov = __shfl_xor(v, m, 64);
    int oi = __shfl_xor(idx, m, 64);
    if (ov < v || (ov == v && oi < idx)) { v = ov; idx = oi; }
  }
  const float* cr = cb + (size_t)idx * DE;
  u16* zr = zq + (size_t)row * DE;
  float s = 0.f;
  #pragma unroll
  for (int i = 0; i < DE / 64; ++i) {
    int e = lane + i * 64;
    float c = cr[e];
    float z = bf2f(zr[e]);
    float d = c - z;
    s += d * d;
    zr[e] = f2bf(c);
  }
  s = wave_sum(s);
  if (lane == 0) atomicAdd(loss, s);
}

__global__ void k_fin(const float* __restrict__ loss, float* __restrict__ out) {
  out[0] = 1.25f * loss[0] * (1.0f / ((float)B_SZ * (float)DE));
}

extern "C" void kernel_launch(void* const* d_in, const int* in_sizes, int n_in,
                              void* d_out, int out_size, void* d_ws, size_t ws_size,
                              hipStream_t stream) {
  const float* x    = (const float*)d_in[0];
  const float* w_in = (const float*)d_in[1];
  const float* b_in = (const float*)d_in[2];
  const float* w_v  = (const float*)d_in[3];
  const float* b_v  = (const float*)d_in[4];
  const float* w_o  = (const float*)d_in[5];
  const float* b_o  = (const float*)d_in[6];
  const float* ln_g = (const float*)d_in[7];
  const float* ln_b = (const float*)d_in[8];
  const float* w1   = (const float*)d_in[9];
  const float* b1   = (const float*)d_in[10];
  const float* w2   = (const float*)d_in[11];
  const float* b2   = (const float*)d_in[12];
  const float* w_cb = (const float*)d_in[13];
  const float* b_cb = (const float*)d_in[14];
  const float* cb   = (const float*)d_in[15];
  const float* w_d1 = (const float*)d_in[16];
  const float* b_d1 = (const float*)d_in[17];
  const float* w_d2 = (const float*)d_in[18];
  const float* b_d2 = (const float*)d_in[19];
  (void)in_sizes; (void)n_in; (void)out_size; (void)ws_size;

  char* ws = (char*)d_ws;
  size_t off = 0;
  auto alloc = [&](size_t n) {
    char* p = ws + off;
    off += (n + 255) & ~(size_t)255;
    return p;
  };
  u16* x_bf = (u16*)alloc((size_t)B_SZ * DIN * 2);  // reused as d1 later
  u16* winb = (u16*)alloc((size_t)DH * DIN * 2);
  u16* wvb  = (u16*)alloc((size_t)DH * DH * 2);
  u16* wob  = (u16*)alloc((size_t)DH * DH * 2);
  u16* w1b  = (u16*)alloc((size_t)DH * DH * 2);
  u16* w2b  = (u16*)alloc((size_t)DH * DH * 2);
  u16* wcbb = (u16*)alloc((size_t)DE * DH * 2);
  u16* cbb  = (u16*)alloc((size_t)KCB * DE * 2);
  u16* wd1b = (u16*)alloc((size_t)DH * DE * 2);
  u16* wd2b = (u16*)alloc((size_t)DIN * DH * 2);
  float* cnorm = (float*)alloc((size_t)KCB * 4);
  u16* S1 = (u16*)alloc((size_t)B_SZ * DH * 2);
  u16* S2 = (u16*)alloc((size_t)B_SZ * DH * 2);
  u16* S3 = (u16*)alloc((size_t)B_SZ * DH * 2);
  u16* zq = (u16*)alloc((size_t)B_SZ * DE * 2);   // z, then quant in-place
  float* partv = (float*)alloc((size_t)B_SZ * 64 * 4);
  int*   parti = (int*)alloc((size_t)B_SZ * 64 * 4);
  float* lossw = (float*)alloc(256);
  u16* d1 = x_bf;

  dim3 blk(256);
  auto cvt = [&](const float* s, u16* d, int n) {
    k_f2bf<<<dim3(n / 1024), blk, 0, stream>>>(s, d, n);
  };
  cvt(x, x_bf, B_SZ * DIN);
  cvt(w_in, winb, DH * DIN);
  cvt(w_v, wvb, DH * DH);
  cvt(w_o, wob, DH * DH);
  cvt(w1, w1b, DH * DH);
  cvt(w2, w2b, DH * DH);
  cvt(w_cb, wcbb, DE * DH);
  cvt(cb, cbb, KCB * DE);
  cvt(w_d1, wd1b, DH * DE);
  cvt(w_d2, wd2b, DIN * DH);
  k_cnorm<<<dim3(KCB / 4), blk, 0, stream>>>(cb, cnorm);

#define GG(M, N) dim3((M) / BM, (N) / BN)
  // h0 = x@w_in^T + b_in
  k_gemm<0><<<GG(B_SZ, DH), blk, 0, stream>>>(x_bf, winb, b_in, nullptr, S1, nullptr,
                                              nullptr, nullptr, nullptr, B_SZ, DH, DIN);
  // v = h0@w_v^T + b_v
  k_gemm<0><<<GG(B_SZ, DH), blk, 0, stream>>>(S1, wvb, b_v, nullptr, S2, nullptr,
                                              nullptr, nullptr, nullptr, B_SZ, DH, DH);
  // attn+h0 = v@w_o^T + b_o + h0
  k_gemm<1><<<GG(B_SZ, DH), blk, 0, stream>>>(S2, wob, b_o, S1, S3, nullptr,
                                              nullptr, nullptr, nullptr, B_SZ, DH, DH);
  // h1 = LN(attn+h0)
  k_ln<<<dim3(B_SZ / 4), blk, 0, stream>>>(S3, ln_g, ln_b, S1);
  // t = relu(h1@w1^T + b1)
  k_gemm<2><<<GG(B_SZ, DH), blk, 0, stream>>>(S1, w1b, b1, nullptr, S2, nullptr,
                                              nullptr, nullptr, nullptr, B_SZ, DH, DH);
  // h2 = relu(t@w2^T + b2) + h1
  k_gemm<3><<<GG(B_SZ, DH), blk, 0, stream>>>(S2, w2b, b2, S1, S3, nullptr,
                                              nullptr, nullptr, nullptr, B_SZ, DH, DH);
  // z = h2@w_cb^T + b_cb
  k_gemm<0><<<GG(B_SZ, DE), blk, 0, stream>>>(S3, wcbb, b_cb, nullptr, zq, nullptr,
                                              nullptr, nullptr, nullptr, B_SZ, DE, DH);
  // distance partials: argmin_c (||c||^2 - 2 z.c) per 128-col block
  k_gemm<5><<<GG(B_SZ, KCB), blk, 0, stream>>>(zq, cbb, nullptr, nullptr, nullptr, nullptr,
                                               cnorm, partv, parti, B_SZ, KCB, DE);
  hipMemsetAsync(lossw, 0, 4, stream);
  // final argmin + gather (z->quant in-place) + loss accumulation
  k_argmin_fin<<<dim3(B_SZ / 4), blk, 0, stream>>>(partv, parti, cb, zq, lossw);
  // d1 = relu(quant@w_d1^T + b_d1)
  k_gemm<2><<<GG(B_SZ, DH), blk, 0, stream>>>(zq, wd1b, b_d1, nullptr, d1, nullptr,
                                              nullptr, nullptr, nullptr, B_SZ, DH, DE);
  // out = relu(d1@w_d2^T + b_d2)  -> f32 d_out
  k_gemm<4><<<GG(B_SZ, DIN), blk, 0, stream>>>(d1, wd2b, b_d2, nullptr, nullptr,
                                               (float*)d_out, nullptr, nullptr, nullptr,
                                               B_SZ, DIN, DH);
  // loss scalar at d_out[B*DIN]
  k_fin<<<dim3(1), dim3(1), 0, stream>>>(lossw, ((float*)d_out) + (size_t)B_SZ * DIN);
#undef GG
}

// Round 2
// 898.054 us; speedup vs baseline: 1.1392x; 1.1392x over previous
//
#include <hip/hip_runtime.h>
#include <stdint.h>

// ---------------------------------------------------------------------------
// VQVAE-with-attention forward, MI355X (gfx950).
// GEMMs: bf16 MFMA 16x16x32, 256x256 tile, BK=32, 8 waves (2x4), 4-deep LDS
// ring with counted vmcnt(8), per-phase raw barriers + setprio, XOR-swizzled
// LDS (both-sides: pre-swizzled global_load_lds source + swizzled ds_read).
// ---------------------------------------------------------------------------

typedef unsigned short u16;
typedef __attribute__((ext_vector_type(8))) short short8;
typedef __attribute__((ext_vector_type(4))) float f32x4;

#define B_SZ 16384
#define DIN 1280
#define DH 1024
#define DE 512
#define KCB 8192

#define BM 256
#define BN 256
#define BKT 32
#define NBUF 4

__device__ __forceinline__ float bf2f(u16 u) {
  union { unsigned int u; float f; } v; v.u = ((unsigned int)u) << 16; return v.f;
}
__device__ __forceinline__ u16 f2bf(float f) {
  union { float f; unsigned int u; } v; v.f = f;
  unsigned int r = v.u + 0x7FFFu + ((v.u >> 16) & 1u);  // RNE
  return (u16)(r >> 16);
}
__device__ __forceinline__ void async16(const u16* g, u16* l) {
  __builtin_amdgcn_global_load_lds((__attribute__((address_space(1))) void*)(g),
                                   (__attribute__((address_space(3))) void*)(l),
                                   16, 0, 0);
}
__device__ __forceinline__ float wave_sum(float s) {
  #pragma unroll
  for (int m = 1; m < 64; m <<= 1) s += __shfl_xor(s, m, 64);
  return s;
}

// f32 -> bf16 conversion, 4 elems/thread
__global__ __launch_bounds__(256) void k_f2bf(const float* __restrict__ in,
                                              u16* __restrict__ out, int n) {
  int i = (blockIdx.x * 256 + threadIdx.x) * 4;
  if (i < n) {
    float4 v = *(const float4*)(in + i);
    ushort4 o;
    o.x = f2bf(v.x); o.y = f2bf(v.y); o.z = f2bf(v.z); o.w = f2bf(v.w);
    *(ushort4*)(out + i) = o;
  }
}

// per-codebook-row squared norms; wave per row
__global__ __launch_bounds__(256) void k_cnorm(const float* __restrict__ cb,
                                               float* __restrict__ cnorm) {
  int row = blockIdx.x * 4 + (threadIdx.x >> 6);
  int lane = threadIdx.x & 63;
  const float* r = cb + (size_t)row * DE;
  float s = 0.f;
  #pragma unroll
  for (int i = 0; i < DE / 64; ++i) { float v = r[lane + i * 64]; s += v * v; }
  s = wave_sum(s);
  if (lane == 0) cnorm[row] = s;
}

// MODE: 0 bias->bf16, 1 bias+res->bf16, 2 bias+relu->bf16,
//       3 bias+relu+res->bf16, 4 bias+relu->f32, 5 argmin partials
template <int MODE>
__global__ __launch_bounds__(512, 2)
void k_gemm(const u16* __restrict__ A, const u16* __restrict__ W,
            const float* __restrict__ bias, const u16* __restrict__ Res,
            u16* __restrict__ O, float* __restrict__ Of,
            const float* __restrict__ cnorm,
            float* __restrict__ partv, int* __restrict__ parti,
            int N, int K, int nNB) {
  __shared__ u16 sbuf[NBUF][2][BM * BKT];  // 4 x (A 16KB + B 16KB) = 128 KB
  const int tid = threadIdx.x;
  const int w = tid >> 6, lane = tid & 63;
  const int wm = w >> 2, wn = w & 3;   // 2 x 4 waves; wave tile 128 x 64
  const int lr = lane & 15, lk = lane >> 4;

  // XCD-bijective swizzle (all grids divisible by 8); bn fastest in orig order
  const int cpx = gridDim.x >> 3;
  const int lin = (blockIdx.x & 7) * cpx + (blockIdx.x >> 3);
  const int bm = lin / nNB, bn = lin % nNB;
  const int m0 = bm * BM, n0 = bn * BN;

  const int NT = K >> 5;  // K-tiles; all K here are multiples of 128 -> NT%4==0

  // staging addressing: thread covers 16B; row = r*128 + srow, slot = lane&3.
  // LDS linear slot s holds logical k-slot (s ^ (row&3) ^ ((row>>2)&3)).
  const int srow = (w << 4) + (lane >> 2);  // 0..127 within a 128-row round
  const int sslot = ((lane & 3) ^ ((lane >> 2) & 3) ^ ((lane >> 4) & 3)) & 3;
  const int doff = srow * BKT + (lane & 3) * 8;
  const u16* Ab = A + (size_t)m0 * K;
  const u16* Bb = W + (size_t)n0 * K;

  // read addressing: frag row = base16 + lr -> row&3 = lane&3, (row>>2)&3 = (lane>>2)&3
  const int rslot8 = ((lk ^ (lane & 3) ^ ((lane >> 2) & 3)) & 3) * 8;

  f32x4 acc[8][4];
  #pragma unroll
  for (int m = 0; m < 8; ++m)
    #pragma unroll
    for (int n = 0; n < 4; ++n) acc[m][n] = (f32x4){0.f, 0.f, 0.f, 0.f};

  auto stage = [&](int buf, int sel, int r, int kt, const u16* Mat) {
    const u16* g = Mat + (size_t)(r * 128 + srow) * K + kt * BKT + sslot * 8;
    async16(g, &sbuf[buf][sel][r * 128 * BKT + doff]);
  };

  // prologue: stage tiles 0,1,2 (12 loads/thread)
  #pragma unroll
  for (int t = 0; t < 3; ++t) {
    stage(t, 0, 0, t, Ab); stage(t, 0, 1, t, Ab);
    stage(t, 1, 0, t, Bb); stage(t, 1, 1, t, Bb);
  }
  asm volatile("s_waitcnt vmcnt(8)" ::: "memory");  // tile 0 arrived (all waves barrier next)
  __builtin_amdgcn_s_barrier();

  for (int g = 0; g < NT; ++g) {
    const int rb = g & 3;
    const int wt = (g + 3 >= NT) ? (g + 3 - NT) : (g + 3);  // wrapped: harmless restage
    const int wb = wt & 3;
    const u16* lA = sbuf[rb][0];
    const u16* lB = sbuf[rb][1];
    short8 af[4], bfr[4];
    // ---- phase 0: ds-load B(all)+A(mh=0), stage next A, barrier, 16 MFMA ----
    #pragma unroll
    for (int n = 0; n < 4; ++n)
      bfr[n] = *(const short8*)&lB[(wn * 64 + n * 16 + lr) * BKT + rslot8];
    #pragma unroll
    for (int m = 0; m < 4; ++m)
      af[m] = *(const short8*)&lA[(wm * 128 + m * 16 + lr) * BKT + rslot8];
    stage(wb, 0, 0, wt, Ab);
    stage(wb, 0, 1, wt, Ab);
    __builtin_amdgcn_s_barrier();
    __builtin_amdgcn_s_setprio(1);
    #pragma unroll
    for (int m = 0; m < 4; ++m)
      #pragma unroll
      for (int n = 0; n < 4; ++n)
        acc[m][n] = __builtin_amdgcn_mfma_f32_16x16x32_bf16(af[m], bfr[n], acc[m][n], 0, 0, 0);
    __builtin_amdgcn_s_setprio(0);
    __builtin_amdgcn_s_barrier();
    // ---- phase 1: ds-load A(mh=1), stage next B, barrier, 16 MFMA ----
    #pragma unroll
    for (int m = 0; m < 4; ++m)
      af[m] = *(const short8*)&lA[(wm * 128 + (m + 4) * 16 + lr) * BKT + rslot8];
    stage(wb, 1, 0, wt, Bb);
    stage(wb, 1, 1, wt, Bb);
    __builtin_amdgcn_s_barrier();
    __builtin_amdgcn_s_setprio(1);
    #pragma unroll
    for (int m = 0; m < 4; ++m)
      #pragma unroll
      for (int n = 0; n < 4; ++n)
        acc[m + 4][n] = __builtin_amdgcn_mfma_f32_16x16x32_bf16(af[m], bfr[n], acc[m + 4][n], 0, 0, 0);
    __builtin_amdgcn_s_setprio(0);
    asm volatile("s_waitcnt vmcnt(8)" ::: "memory");  // tile g+1 arrived; g+2,g+3 in flight
    __builtin_amdgcn_s_barrier();
  }
  __syncthreads();  // full drain before epilogue / LDS reuse

  if constexpr (MODE == 5) {
    float* sv = (float*)&sbuf[0][0][0];     // [4][256]
    int*   si = (int*)(sv + 4 * 256);
    float cn[4];
    int gcn[4];
    #pragma unroll
    for (int n = 0; n < 4; ++n) {
      gcn[n] = n0 + wn * 64 + n * 16 + lr;
      cn[n] = cnorm[gcn[n]];
    }
    #pragma unroll
    for (int m = 0; m < 8; ++m) {
      #pragma unroll
      for (int j = 0; j < 4; ++j) {
        float bv = 3.0e38f; int bc = 0;
        #pragma unroll
        for (int n = 0; n < 4; ++n) {
          float v = cn[n] - 2.0f * acc[m][n][j];
          if (v < bv || (v == bv && gcn[n] < bc)) { bv = v; bc = gcn[n]; }
        }
        #pragma unroll
        for (int mask = 1; mask < 16; mask <<= 1) {
          float ov = __shfl_xor(bv, mask, 64);
          int oc = __shfl_xor(bc, mask, 64);
          if (ov < bv || (ov == bv && oc < bc)) { bv = ov; bc = oc; }
        }
        if (lr == 0) {
          int row = wm * 128 + m * 16 + lk * 4 + j;
          sv[wn * 256 + row] = bv; si[wn * 256 + row] = bc;
        }
      }
    }
    __syncthreads();
    if (tid < 256) {
      float v = sv[tid]; int ii = si[tid];
      #pragma unroll
      for (int q = 1; q < 4; ++q) {
        float ov = sv[q * 256 + tid]; int oi = si[q * 256 + tid];
        if (ov < v || (ov == v && oi < ii)) { v = ov; ii = oi; }
      }
      partv[(size_t)(m0 + tid) * nNB + bn] = v;
      parti[(size_t)(m0 + tid) * nNB + bn] = ii;
    }
  } else {
    float bb4[4];
    #pragma unroll
    for (int n = 0; n < 4; ++n) bb4[n] = bias[n0 + wn * 64 + n * 16 + lr];
    #pragma unroll
    for (int m = 0; m < 8; ++m) {
      int gr = m0 + wm * 128 + m * 16 + lk * 4;
      #pragma unroll
      for (int n = 0; n < 4; ++n) {
        int gc = n0 + wn * 64 + n * 16 + lr;
        #pragma unroll
        for (int j = 0; j < 4; ++j) {
          float v = acc[m][n][j] + bb4[n];
          if constexpr (MODE == 2 || MODE == 3 || MODE == 4) v = fmaxf(v, 0.f);
          if constexpr (MODE == 1 || MODE == 3) v += bf2f(Res[(size_t)(gr + j) * N + gc]);
          if constexpr (MODE == 4) Of[(size_t)(gr + j) * N + gc] = v;
          else O[(size_t)(gr + j) * N + gc] = f2bf(v);
        }
      }
    }
  }
}

// LayerNorm over DH=1024, wave per row, 16 elems/lane
__global__ __launch_bounds__(256)
void k_ln(const u16* __restrict__ X, const float* __restrict__ g,
          const float* __restrict__ b, u16* __restrict__ O) {
  int row = blockIdx.x * 4 + (threadIdx.x >> 6);
  int lane = threadIdx.x & 63;
  const u16* xr = X + (size_t)row * DH + lane * 16;
  uint4 d0 = *(const uint4*)(xr);
  uint4 d1 = *(const uint4*)(xr + 8);
  unsigned int ww[8] = {d0.x, d0.y, d0.z, d0.w, d1.x, d1.y, d1.z, d1.w};
  float v[16];
  #pragma unroll
  for (int i = 0; i < 8; ++i) {
    v[2 * i] = bf2f((u16)(ww[i] & 0xffff));
    v[2 * i + 1] = bf2f((u16)(ww[i] >> 16));
  }
  float s = 0.f;
  #pragma unroll
  for (int i = 0; i < 16; ++i) s += v[i];
  s = wave_sum(s);
  float mean = s * (1.0f / DH);
  float q = 0.f;
  #pragma unroll
  for (int i = 0; i < 16; ++i) { float d = v[i] - mean; q += d * d; }
  q = wave_sum(q);
  float rstd = rsqrtf(q * (1.0f / DH) + 1e-5f);
  int base = lane * 16;
  unsigned int ow[8];
  #pragma unroll
  for (int i = 0; i < 8; ++i) {
    float a0 = (v[2 * i] - mean) * rstd * g[base + 2 * i] + b[base + 2 * i];
    float a1 = (v[2 * i + 1] - mean) * rstd * g[base + 2 * i + 1] + b[base + 2 * i + 1];
    ow[i] = (unsigned int)f2bf(a0) | ((unsigned int)f2bf(a1) << 16);
  }
  uint4 o0 = {ow[0], ow[1], ow[2], ow[3]};
  uint4 o1 = {ow[4], ow[5], ow[6], ow[7]};
  *(uint4*)(O + (size_t)row * DH + lane * 16) = o0;
  *(uint4*)(O + (size_t)row * DH + lane * 16 + 8) = o1;
}

// final argmin over 32 partials/row, gather codebook row (overwrite z with
// quant in-place), accumulate sum((quant-z)^2)
__global__ __launch_bounds__(256)
void k_argmin_fin(const float* __restrict__ partv, const int* __restrict__ parti,
                  const float* __restrict__ cb, u16* __restrict__ zq,
                  float* __restrict__ loss) {
  int row = blockIdx.x * 4 + (threadIdx.x >> 6);
  int lane = threadIdx.x & 63;
  float v = 3.0e38f; int idx = 0;
  if (lane < 32) {
    v = partv[(size_t)row * 32 + lane];
    idx = parti[(size_t)row * 32 + lane];
  }
  #pragma unroll
  for (int m = 1; m < 64; m <<= 1) {
    float ov = __shfl_xor(v, m, 64);
    int oi = __shfl_xor(idx, m, 64);
    if (ov < v || (ov == v && oi < idx)) { v = ov; idx = oi; }
  }
  const float* cr = cb + (size_t)idx * DE;
  u16* zr = zq + (size_t)row * DE;
  float s = 0.f;
  #pragma unroll
  for (int i = 0; i < DE / 64; ++i) {
    int e = lane + i * 64;
    float c = cr[e];
    float z = bf2f(zr[e]);
    float d = c - z;
    s += d * d;
    zr[e] = f2bf(c);
  }
  s = wave_sum(s);
  if (lane == 0) atomicAdd(loss, s);
}

__global__ void k_fin(const float* __restrict__ loss, float* __restrict__ out) {
  out[0] = 1.25f * loss[0] * (1.0f / ((float)B_SZ * (float)DE));
}

extern "C" void kernel_launch(void* const* d_in, const int* in_sizes, int n_in,
                              void* d_out, int out_size, void* d_ws, size_t ws_size,
                              hipStream_t stream) {
  const float* x    = (const float*)d_in[0];
  const float* w_in = (const float*)d_in[1];
  const float* b_in = (const float*)d_in[2];
  const float* w_v  = (const float*)d_in[3];
  const float* b_v  = (const float*)d_in[4];
  const float* w_o  = (const float*)d_in[5];
  const float* b_o  = (const float*)d_in[6];
  const float* ln_g = (const float*)d_in[7];
  const float* ln_b = (const float*)d_in[8];
  const float* w1   = (const float*)d_in[9];
  const float* b1   = (const float*)d_in[10];
  const float* w2   = (const float*)d_in[11];
  const float* b2   = (const float*)d_in[12];
  const float* w_cb = (const float*)d_in[13];
  const float* b_cb = (const float*)d_in[14];
  const float* cb   = (const float*)d_in[15];
  const float* w_d1 = (const float*)d_in[16];
  const float* b_d1 = (const float*)d_in[17];
  const float* w_d2 = (const float*)d_in[18];
  const float* b_d2 = (const float*)d_in[19];
  (void)in_sizes; (void)n_in; (void)out_size; (void)ws_size;

  char* ws = (char*)d_ws;
  size_t off = 0;
  auto alloc = [&](size_t n) {
    char* p = ws + off;
    off += (n + 255) & ~(size_t)255;
    return p;
  };
  u16* x_bf = (u16*)alloc((size_t)B_SZ * DIN * 2);  // reused as d1 later
  u16* winb = (u16*)alloc((size_t)DH * DIN * 2);
  u16* wvb  = (u16*)alloc((size_t)DH * DH * 2);
  u16* wob  = (u16*)alloc((size_t)DH * DH * 2);
  u16* w1b  = (u16*)alloc((size_t)DH * DH * 2);
  u16* w2b  = (u16*)alloc((size_t)DH * DH * 2);
  u16* wcbb = (u16*)alloc((size_t)DE * DH * 2);
  u16* cbb  = (u16*)alloc((size_t)KCB * DE * 2);
  u16* wd1b = (u16*)alloc((size_t)DH * DE * 2);
  u16* wd2b = (u16*)alloc((size_t)DIN * DH * 2);
  float* cnorm = (float*)alloc((size_t)KCB * 4);
  u16* S1 = (u16*)alloc((size_t)B_SZ * DH * 2);
  u16* S2 = (u16*)alloc((size_t)B_SZ * DH * 2);
  u16* S3 = (u16*)alloc((size_t)B_SZ * DH * 2);
  u16* zq = (u16*)alloc((size_t)B_SZ * DE * 2);   // z, then quant in-place
  float* partv = (float*)alloc((size_t)B_SZ * 32 * 4);
  int*   parti = (int*)alloc((size_t)B_SZ * 32 * 4);
  float* lossw = (float*)alloc(256);
  u16* d1 = x_bf;

  dim3 blk(256);
  auto cvt = [&](const float* s, u16* d, int n) {
    k_f2bf<<<dim3(n / 1024), blk, 0, stream>>>(s, d, n);
  };
  cvt(x, x_bf, B_SZ * DIN);
  cvt(w_in, winb, DH * DIN);
  cvt(w_v, wvb, DH * DH);
  cvt(w_o, wob, DH * DH);
  cvt(w1, w1b, DH * DH);
  cvt(w2, w2b, DH * DH);
  cvt(w_cb, wcbb, DE * DH);
  cvt(cb, cbb, KCB * DE);
  cvt(w_d1, wd1b, DH * DE);
  cvt(w_d2, wd2b, DIN * DH);
  k_cnorm<<<dim3(KCB / 4), blk, 0, stream>>>(cb, cnorm);

  dim3 gblk(512);
#define GG(N) dim3((B_SZ / BM) * ((N) / BN))
  // h0 = x@w_in^T + b_in
  k_gemm<0><<<GG(DH), gblk, 0, stream>>>(x_bf, winb, b_in, nullptr, S1, nullptr,
                                         nullptr, nullptr, nullptr, DH, DIN, DH / BN);
  // v = h0@w_v^T + b_v
  k_gemm<0><<<GG(DH), gblk, 0, stream>>>(S1, wvb, b_v, nullptr, S2, nullptr,
                                         nullptr, nullptr, nullptr, DH, DH, DH / BN);
  // attn+h0 = v@w_o^T + b_o + h0
  k_gemm<1><<<GG(DH), gblk, 0, stream>>>(S2, wob, b_o, S1, S3, nullptr,
                                         nullptr, nullptr, nullptr, DH, DH, DH / BN);
  // h1 = LN(attn+h0)
  k_ln<<<dim3(B_SZ / 4), blk, 0, stream>>>(S3, ln_g, ln_b, S1);
  // t = relu(h1@w1^T + b1)
  k_gemm<2><<<GG(DH), gblk, 0, stream>>>(S1, w1b, b1, nullptr, S2, nullptr,
                                         nullptr, nullptr, nullptr, DH, DH, DH / BN);
  // h2 = relu(t@w2^T + b2) + h1
  k_gemm<3><<<GG(DH), gblk, 0, stream>>>(S2, w2b, b2, S1, S3, nullptr,
                                         nullptr, nullptr, nullptr, DH, DH, DH / BN);
  // z = h2@w_cb^T + b_cb
  k_gemm<0><<<GG(DE), gblk, 0, stream>>>(S3, wcbb, b_cb, nullptr, zq, nullptr,
                                         nullptr, nullptr, nullptr, DE, DH, DE / BN);
  // distance partials: argmin_c (||c||^2 - 2 z.c) per 256-col block
  k_gemm<5><<<GG(KCB), gblk, 0, stream>>>(zq, cbb, nullptr, nullptr, nullptr, nullptr,
                                          cnorm, partv, parti, KCB, DE, KCB / BN);
  hipMemsetAsync(lossw, 0, 4, stream);
  // final argmin + gather (z->quant in-place) + loss accumulation
  k_argmin_fin<<<dim3(B_SZ / 4), blk, 0, stream>>>(partv, parti, cb, zq, lossw);
  // d1 = relu(quant@w_d1^T + b_d1)
  k_gemm<2><<<GG(DH), gblk, 0, stream>>>(zq, wd1b, b_d1, nullptr, d1, nullptr,
                                         nullptr, nullptr, nullptr, DH, DE, DH / BN);
  // out = relu(d1@w_d2^T + b_d2)  -> f32 d_out
  k_gemm<4><<<GG(DIN), gblk, 0, stream>>>(d1, wd2b, b_d2, nullptr, nullptr,
                                          (float*)d_out, nullptr, nullptr, nullptr,
                                          DIN, DH, DIN / BN);
  // loss scalar at d_out[B*DIN]
  k_fin<<<dim3(1), dim3(1), 0, stream>>>(lossw, ((float*)d_out) + (size_t)B_SZ * DIN);
#undef GG
}

// Round 3
// 832.898 us; speedup vs baseline: 1.2284x; 1.0782x over previous
//
#include <hip/hip_runtime.h>
#include <stdint.h>

// ---------------------------------------------------------------------------
// VQVAE-with-attention forward, MI355X (gfx950).
// GEMMs: bf16 MFMA 16x16x32, 256x256 tile, BK=64, 8 waves (2x4), 2-buffer LDS
// (T3-minimum template): stage tile t+1 at top, compute tile t, vmcnt(0)+
// barrier at bottom. XOR-swizzled LDS (slot ^= row&7), pre-swizzled global
// source + swizzled ds_read base; induction-variable addressing throughout.
// ---------------------------------------------------------------------------

typedef unsigned short u16;
typedef __attribute__((ext_vector_type(8))) short short8;
typedef __attribute__((ext_vector_type(4))) float f32x4;

#define B_SZ 16384
#define DIN 1280
#define DH 1024
#define DE 512
#define KCB 8192

#define BM 256
#define BN 256
#define BK 64

__device__ __forceinline__ float bf2f(u16 u) {
  union { unsigned int u; float f; } v; v.u = ((unsigned int)u) << 16; return v.f;
}
__device__ __forceinline__ u16 f2bf(float f) {
  union { float f; unsigned int u; } v; v.f = f;
  unsigned int r = v.u + 0x7FFFu + ((v.u >> 16) & 1u);  // RNE
  return (u16)(r >> 16);
}
__device__ __forceinline__ void async16(const u16* g, u16* l) {
  __builtin_amdgcn_global_load_lds((__attribute__((address_space(1))) void*)(g),
                                   (__attribute__((address_space(3))) void*)(l),
                                   16, 0, 0);
}
__device__ __forceinline__ float wave_sum(float s) {
  #pragma unroll
  for (int m = 1; m < 64; m <<= 1) s += __shfl_xor(s, m, 64);
  return s;
}

// f32 -> bf16 conversion, 4 elems/thread
__global__ __launch_bounds__(256) void k_f2bf(const float* __restrict__ in,
                                              u16* __restrict__ out, int n) {
  int i = (blockIdx.x * 256 + threadIdx.x) * 4;
  if (i < n) {
    float4 v = *(const float4*)(in + i);
    ushort4 o;
    o.x = f2bf(v.x); o.y = f2bf(v.y); o.z = f2bf(v.z); o.w = f2bf(v.w);
    *(ushort4*)(out + i) = o;
  }
}

// per-codebook-row squared norms; wave per row
__global__ __launch_bounds__(256) void k_cnorm(const float* __restrict__ cb,
                                               float* __restrict__ cnorm) {
  int row = blockIdx.x * 4 + (threadIdx.x >> 6);
  int lane = threadIdx.x & 63;
  const float* r = cb + (size_t)row * DE;
  float s = 0.f;
  #pragma unroll
  for (int i = 0; i < DE / 64; ++i) { float v = r[lane + i * 64]; s += v * v; }
  s = wave_sum(s);
  if (lane == 0) cnorm[row] = s;
}

// MODE: 0 bias->bf16, 1 bias+res->bf16, 2 bias+relu->bf16,
//       3 bias+relu+res->bf16, 4 bias+relu->f32, 5 argmin partials
template <int MODE>
__global__ __launch_bounds__(512, 2)
void k_gemm(const u16* __restrict__ A, const u16* __restrict__ W,
            const float* __restrict__ bias, const u16* __restrict__ Res,
            u16* __restrict__ O, float* __restrict__ Of,
            const float* __restrict__ cnorm,
            float* __restrict__ partv, int* __restrict__ parti,
            int N, int K, int nNB) {
  // 128 KB: buf{0,1} x (A 16K elems, B 16K elems). Row-major [row][k] per
  // matrix, 64 elems (128B = 8 x 16B slots) per row; slot XOR-swizzled by row&7.
  __shared__ u16 sbuf[2 * 32768];
  const int tid = threadIdx.x;
  const int w = tid >> 6, lane = tid & 63;
  const int wm = w >> 2, wn = w & 3;   // 2 x 4 waves; wave tile 128 x 64
  const int lr = lane & 15, lk = lane >> 4;

  // XCD-bijective swizzle (all grids divisible by 8)
  const int cpx = gridDim.x >> 3;
  const int lin = (blockIdx.x & 7) * cpx + (blockIdx.x >> 3);
  const int bm = lin / nNB, bn = lin % nNB;
  const int m0 = bm * BM, n0 = bn * BN;
  const int NT = K >> 6;

  // staging: thread covers 16B. LDS linear elem = mat*16384 + c*4096 + tid*8
  // -> row = c*64 + (tid>>3), linear slot = tid&7; logical kslot = slot^(row&7)
  const int srow = tid >> 3;
  const int sks = ((tid & 7) ^ (srow & 7)) * 8;
  const u16* gA = A + (m0 + srow) * K + sks;
  const u16* gB = W + (n0 + srow) * K + sks;
  const int K64 = K * 64;
  u16* const sT = sbuf + tid * 8;

  // read bases (elem units), swizzled: slot(ks) = ((ks*4+lk) ^ (lr&7)) * 8
  const int arow = (wm * 128 + lr) * 64;
  const int brow = 16384 + (wn * 64 + lr) * 64;
  const int sl0 = ((lk ^ (lr & 7)) & 7) * 8;
  const int sl1 = (((4 + lk) ^ (lr & 7)) & 7) * 8;

  f32x4 acc[8][4];
  #pragma unroll
  for (int m = 0; m < 8; ++m)
    #pragma unroll
    for (int n = 0; n < 4; ++n) acc[m][n] = (f32x4){0.f, 0.f, 0.f, 0.f};

  // prologue: stage tile 0 into buf 0
  #pragma unroll
  for (int c = 0; c < 4; ++c) {
    async16(gA + c * K64, sT + c * 4096);
    async16(gB + c * K64, sT + 16384 + c * 4096);
  }
  gA += 64; gB += 64;
  asm volatile("s_waitcnt vmcnt(0)" ::: "memory");
  __builtin_amdgcn_s_barrier();

  int boff = 0;
  for (int t = 0; t < NT; ++t) {
    if (t + 1 < NT) {
      u16* d = sT + (boff ^ 32768);
      #pragma unroll
      for (int c = 0; c < 4; ++c) {
        async16(gA + c * K64, d + c * 4096);
        async16(gB + c * K64, d + 16384 + c * 4096);
      }
      gA += 64; gB += 64;
    }
    #pragma unroll
    for (int ks = 0; ks < 2; ++ks) {
      const u16* ab = sbuf + boff + arow + (ks ? sl1 : sl0);
      const u16* bb = sbuf + boff + brow + (ks ? sl1 : sl0);
      short8 af[8], bfr[4];
      #pragma unroll
      for (int m = 0; m < 8; ++m) af[m] = *(const short8*)(ab + m * 1024);
      #pragma unroll
      for (int n = 0; n < 4; ++n) bfr[n] = *(const short8*)(bb + n * 1024);
      __builtin_amdgcn_s_setprio(1);
      #pragma unroll
      for (int m = 0; m < 8; ++m)
        #pragma unroll
        for (int n = 0; n < 4; ++n)
          acc[m][n] = __builtin_amdgcn_mfma_f32_16x16x32_bf16(af[m], bfr[n], acc[m][n], 0, 0, 0);
      __builtin_amdgcn_s_setprio(0);
    }
    asm volatile("s_waitcnt vmcnt(0)" ::: "memory");
    __builtin_amdgcn_s_barrier();
    boff ^= 32768;
  }
  __syncthreads();

  if constexpr (MODE == 5) {
    float* sv = (float*)&sbuf[0];            // [4][256] f32
    int*   si = (int*)(sv + 4 * 256);        // [4][256] i32
    float cn[4];
    int gcn[4];
    #pragma unroll
    for (int n = 0; n < 4; ++n) {
      gcn[n] = n0 + wn * 64 + n * 16 + lr;
      cn[n] = cnorm[gcn[n]];
    }
    #pragma unroll
    for (int m = 0; m < 8; ++m) {
      #pragma unroll
      for (int j = 0; j < 4; ++j) {
        float bv = 3.0e38f; int bc = 0;
        #pragma unroll
        for (int n = 0; n < 4; ++n) {
          float v = cn[n] - 2.0f * acc[m][n][j];
          if (v < bv || (v == bv && gcn[n] < bc)) { bv = v; bc = gcn[n]; }
        }
        #pragma unroll
        for (int mask = 1; mask < 16; mask <<= 1) {
          float ov = __shfl_xor(bv, mask, 64);
          int oc = __shfl_xor(bc, mask, 64);
          if (ov < bv || (ov == bv && oc < bc)) { bv = ov; bc = oc; }
        }
        if (lr == 0) {
          int row = wm * 128 + m * 16 + lk * 4 + j;
          sv[wn * 256 + row] = bv; si[wn * 256 + row] = bc;
        }
      }
    }
    __syncthreads();
    if (tid < 256) {
      float v = sv[tid]; int ii = si[tid];
      #pragma unroll
      for (int q = 1; q < 4; ++q) {
        float ov = sv[q * 256 + tid]; int oi = si[q * 256 + tid];
        if (ov < v || (ov == v && oi < ii)) { v = ov; ii = oi; }
      }
      partv[(size_t)(m0 + tid) * nNB + bn] = v;
      parti[(size_t)(m0 + tid) * nNB + bn] = ii;
    }
  } else {
    float bb4[4];
    #pragma unroll
    for (int n = 0; n < 4; ++n) bb4[n] = bias[n0 + wn * 64 + n * 16 + lr];
    #pragma unroll
    for (int m = 0; m < 8; ++m) {
      int gr = m0 + wm * 128 + m * 16 + lk * 4;
      #pragma unroll
      for (int n = 0; n < 4; ++n) {
        int gc = n0 + wn * 64 + n * 16 + lr;
        #pragma unroll
        for (int j = 0; j < 4; ++j) {
          float v = acc[m][n][j] + bb4[n];
          if constexpr (MODE == 2 || MODE == 3 || MODE == 4) v = fmaxf(v, 0.f);
          if constexpr (MODE == 1 || MODE == 3) v += bf2f(Res[(size_t)(gr + j) * N + gc]);
          if constexpr (MODE == 4) Of[(size_t)(gr + j) * N + gc] = v;
          else O[(size_t)(gr + j) * N + gc] = f2bf(v);
        }
      }
    }
  }
}

// LayerNorm over DH=1024, wave per row, 16 elems/lane
__global__ __launch_bounds__(256)
void k_ln(const u16* __restrict__ X, const float* __restrict__ g,
          const float* __restrict__ b, u16* __restrict__ O) {
  int row = blockIdx.x * 4 + (threadIdx.x >> 6);
  int lane = threadIdx.x & 63;
  const u16* xr = X + (size_t)row * DH + lane * 16;
  uint4 d0 = *(const uint4*)(xr);
  uint4 d1 = *(const uint4*)(xr + 8);
  unsigned int ww[8] = {d0.x, d0.y, d0.z, d0.w, d1.x, d1.y, d1.z, d1.w};
  float v[16];
  #pragma unroll
  for (int i = 0; i < 8; ++i) {
    v[2 * i] = bf2f((u16)(ww[i] & 0xffff));
    v[2 * i + 1] = bf2f((u16)(ww[i] >> 16));
  }
  float s = 0.f;
  #pragma unroll
  for (int i = 0; i < 16; ++i) s += v[i];
  s = wave_sum(s);
  float mean = s * (1.0f / DH);
  float q = 0.f;
  #pragma unroll
  for (int i = 0; i < 16; ++i) { float d = v[i] - mean; q += d * d; }
  q = wave_sum(q);
  float rstd = rsqrtf(q * (1.0f / DH) + 1e-5f);
  int base = lane * 16;
  unsigned int ow[8];
  #pragma unroll
  for (int i = 0; i < 8; ++i) {
    float a0 = (v[2 * i] - mean) * rstd * g[base + 2 * i] + b[base + 2 * i];
    float a1 = (v[2 * i + 1] - mean) * rstd * g[base + 2 * i + 1] + b[base + 2 * i + 1];
    ow[i] = (unsigned int)f2bf(a0) | ((unsigned int)f2bf(a1) << 16);
  }
  uint4 o0 = {ow[0], ow[1], ow[2], ow[3]};
  uint4 o1 = {ow[4], ow[5], ow[6], ow[7]};
  *(uint4*)(O + (size_t)row * DH + lane * 16) = o0;
  *(uint4*)(O + (size_t)row * DH + lane * 16 + 8) = o1;
}

// final argmin over 32 partials/row, gather codebook row (overwrite z with
// quant in-place), accumulate sum((quant-z)^2)
__global__ __launch_bounds__(256)
void k_argmin_fin(const float* __restrict__ partv, const int* __restrict__ parti,
                  const float* __restrict__ cb, u16* __restrict__ zq,
                  float* __restrict__ loss) {
  int row = blockIdx.x * 4 + (threadIdx.x >> 6);
  int lane = threadIdx.x & 63;
  float v = 3.0e38f; int idx = 0;
  if (lane < 32) {
    v = partv[(size_t)row * 32 + lane];
    idx = parti[(size_t)row * 32 + lane];
  }
  #pragma unroll
  for (int m = 1; m < 64; m <<= 1) {
    float ov = __shfl_xor(v, m, 64);
    int oi = __shfl_xor(idx, m, 64);
    if (ov < v || (ov == v && oi < idx)) { v = ov; idx = oi; }
  }
  const float* cr = cb + (size_t)idx * DE;
  u16* zr = zq + (size_t)row * DE;
  float s = 0.f;
  #pragma unroll
  for (int i = 0; i < DE / 64; ++i) {
    int e = lane + i * 64;
    float c = cr[e];
    float z = bf2f(zr[e]);
    float d = c - z;
    s += d * d;
    zr[e] = f2bf(c);
  }
  s = wave_sum(s);
  if (lane == 0) atomicAdd(loss, s);
}

__global__ void k_fin(const float* __restrict__ loss, float* __restrict__ out) {
  out[0] = 1.25f * loss[0] * (1.0f / ((float)B_SZ * (float)DE));
}

extern "C" void kernel_launch(void* const* d_in, const int* in_sizes, int n_in,
                              void* d_out, int out_size, void* d_ws, size_t ws_size,
                              hipStream_t stream) {
  const float* x    = (const float*)d_in[0];
  const float* w_in = (const float*)d_in[1];
  const float* b_in = (const float*)d_in[2];
  const float* w_v  = (const float*)d_in[3];
  const float* b_v  = (const float*)d_in[4];
  const float* w_o  = (const float*)d_in[5];
  const float* b_o  = (const float*)d_in[6];
  const float* ln_g = (const float*)d_in[7];
  const float* ln_b = (const float*)d_in[8];
  const float* w1   = (const float*)d_in[9];
  const float* b1   = (const float*)d_in[10];
  const float* w2   = (const float*)d_in[11];
  const float* b2   = (const float*)d_in[12];
  const float* w_cb = (const float*)d_in[13];
  const float* b_cb = (const float*)d_in[14];
  const float* cb   = (const float*)d_in[15];
  const float* w_d1 = (const float*)d_in[16];
  const float* b_d1 = (const float*)d_in[17];
  const float* w_d2 = (const float*)d_in[18];
  const float* b_d2 = (const float*)d_in[19];
  (void)in_sizes; (void)n_in; (void)out_size; (void)ws_size;

  char* ws = (char*)d_ws;
  size_t off = 0;
  auto alloc = [&](size_t n) {
    char* p = ws + off;
    off += (n + 255) & ~(size_t)255;
    return p;
  };
  u16* x_bf = (u16*)alloc((size_t)B_SZ * DIN * 2);  // reused as d1 later
  u16* winb = (u16*)alloc((size_t)DH * DIN * 2);
  u16* wvb  = (u16*)alloc((size_t)DH * DH * 2);
  u16* wob  = (u16*)alloc((size_t)DH * DH * 2);
  u16* w1b  = (u16*)alloc((size_t)DH * DH * 2);
  u16* w2b  = (u16*)alloc((size_t)DH * DH * 2);
  u16* wcbb = (u16*)alloc((size_t)DE * DH * 2);
  u16* cbb  = (u16*)alloc((size_t)KCB * DE * 2);
  u16* wd1b = (u16*)alloc((size_t)DH * DE * 2);
  u16* wd2b = (u16*)alloc((size_t)DIN * DH * 2);
  float* cnorm = (float*)alloc((size_t)KCB * 4);
  u16* S1 = (u16*)alloc((size_t)B_SZ * DH * 2);
  u16* S2 = (u16*)alloc((size_t)B_SZ * DH * 2);
  u16* S3 = (u16*)alloc((size_t)B_SZ * DH * 2);
  u16* zq = (u16*)alloc((size_t)B_SZ * DE * 2);   // z, then quant in-place
  float* partv = (float*)alloc((size_t)B_SZ * 32 * 4);
  int*   parti = (int*)alloc((size_t)B_SZ * 32 * 4);
  float* lossw = (float*)alloc(256);
  u16* d1 = x_bf;

  dim3 blk(256);
  auto cvt = [&](const float* s, u16* d, int n) {
    k_f2bf<<<dim3(n / 1024), blk, 0, stream>>>(s, d, n);
  };
  cvt(x, x_bf, B_SZ * DIN);
  cvt(w_in, winb, DH * DIN);
  cvt(w_v, wvb, DH * DH);
  cvt(w_o, wob, DH * DH);
  cvt(w1, w1b, DH * DH);
  cvt(w2, w2b, DH * DH);
  cvt(w_cb, wcbb, DE * DH);
  cvt(cb, cbb, KCB * DE);
  cvt(w_d1, wd1b, DH * DE);
  cvt(w_d2, wd2b, DIN * DH);
  k_cnorm<<<dim3(KCB / 4), blk, 0, stream>>>(cb, cnorm);

  dim3 gblk(512);
#define GG(N) dim3((B_SZ / BM) * ((N) / BN))
  // h0 = x@w_in^T + b_in
  k_gemm<0><<<GG(DH), gblk, 0, stream>>>(x_bf, winb, b_in, nullptr, S1, nullptr,
                                         nullptr, nullptr, nullptr, DH, DIN, DH / BN);
  // v = h0@w_v^T + b_v
  k_gemm<0><<<GG(DH), gblk, 0, stream>>>(S1, wvb, b_v, nullptr, S2, nullptr,
                                         nullptr, nullptr, nullptr, DH, DH, DH / BN);
  // attn+h0 = v@w_o^T + b_o + h0
  k_gemm<1><<<GG(DH), gblk, 0, stream>>>(S2, wob, b_o, S1, S3, nullptr,
                                         nullptr, nullptr, nullptr, DH, DH, DH / BN);
  // h1 = LN(attn+h0)
  k_ln<<<dim3(B_SZ / 4), blk, 0, stream>>>(S3, ln_g, ln_b, S1);
  // t = relu(h1@w1^T + b1)
  k_gemm<2><<<GG(DH), gblk, 0, stream>>>(S1, w1b, b1, nullptr, S2, nullptr,
                                         nullptr, nullptr, nullptr, DH, DH, DH / BN);
  // h2 = relu(t@w2^T + b2) + h1
  k_gemm<3><<<GG(DH), gblk, 0, stream>>>(S2, w2b, b2, S1, S3, nullptr,
                                         nullptr, nullptr, nullptr, DH, DH, DH / BN);
  // z = h2@w_cb^T + b_cb
  k_gemm<0><<<GG(DE), gblk, 0, stream>>>(S3, wcbb, b_cb, nullptr, zq, nullptr,
                                         nullptr, nullptr, nullptr, DE, DH, DE / BN);
  // distance partials: argmin_c (||c||^2 - 2 z.c) per 256-col block
  k_gemm<5><<<GG(KCB), gblk, 0, stream>>>(zq, cbb, nullptr, nullptr, nullptr, nullptr,
                                          cnorm, partv, parti, KCB, DE, KCB / BN);
  hipMemsetAsync(lossw, 0, 4, stream);
  // final argmin + gather (z->quant in-place) + loss accumulation
  k_argmin_fin<<<dim3(B_SZ / 4), blk, 0, stream>>>(partv, parti, cb, zq, lossw);
  // d1 = relu(quant@w_d1^T + b_d1)
  k_gemm<2><<<GG(DH), gblk, 0, stream>>>(zq, wd1b, b_d1, nullptr, d1, nullptr,
                                         nullptr, nullptr, nullptr, DH, DE, DH / BN);
  // out = relu(d1@w_d2^T + b_d2)  -> f32 d_out
  k_gemm<4><<<GG(DIN), gblk, 0, stream>>>(d1, wd2b, b_d2, nullptr, nullptr,
                                          (float*)d_out, nullptr, nullptr, nullptr,
                                          DIN, DH, DIN / BN);
  // loss scalar at d_out[B*DIN]
  k_fin<<<dim3(1), dim3(1), 0, stream>>>(lossw, ((float*)d_out) + (size_t)B_SZ * DIN);
#undef GG
}